// Round 9
// baseline (228.742 us; speedup 1.0000x reference)
//
#include <hip/hip_runtime.h>
#include <math.h>

#define HW 4096
#define CH 128
#define NH 4
#define DH 32

typedef unsigned short u16;
typedef __attribute__((ext_vector_type(8))) short bf16x8;   // 8 bf16 in 4 VGPRs
typedef __attribute__((ext_vector_type(4))) float f32x4;
typedef __attribute__((ext_vector_type(16))) float f32x16;
typedef __attribute__((ext_vector_type(4))) unsigned short u16x4;
typedef __attribute__((ext_vector_type(8))) unsigned short u16x8;

// raw v_exp_f32 (args are in [-1,1]; no range fixups needed)
#if __has_builtin(__builtin_amdgcn_exp2f)
#define KFOLD (0.17677669529663687f * 1.4426950408889634f)   // scale * log2(e)
#define FASTEXP(x) __builtin_amdgcn_exp2f(x)
#else
#define KFOLD 0.17677669529663687f                            // scale only
#define FASTEXP(x) __expf(x)
#endif

#if __has_builtin(__builtin_amdgcn_rcpf)
#define RCPF(x) __builtin_amdgcn_rcpf(x)
#else
#define RCPF(x) (1.f / (x))
#endif

__device__ __forceinline__ u16 f2bf(float f) {
    union { float f; unsigned u; } a; a.f = f;
    unsigned u = a.u;
    unsigned r = u + 0x7FFFu + ((u >> 16) & 1u);   // RNE
    return (u16)(r >> 16);
}
__device__ __forceinline__ float bf2f(u16 u) {
    union { unsigned u; float f; } a; a.u = ((unsigned)u) << 16;
    return a.f;
}
// pack two positive floats to bf16 pair by TRUNCATION (1 v_perm): low=a, high=b
__device__ __forceinline__ unsigned pack2bf_t(float a, float b) {
    union { float f; unsigned u; } ua, ub; ua.f = a; ub.f = b;
    return __builtin_amdgcn_perm(ub.u, ua.u, 0x07060302u);
}

// ---------------- Fused: weight frag-swizzle conversion + GN partials -----
// Weights are stored in MFMA A-fragment order: [(wave*NOS+os)*4+kc][lane][8]
// so consumer waves load one contiguous 1KB stream per fragment.
__global__ __launch_bounds__(256) void prep_kernel(
    const float* __restrict__ x, float* __restrict__ partials,
    const float* __restrict__ qkv_w, const float* __restrict__ proj_w,
    u16* __restrict__ wq, u16* __restrict__ wp) {
    int blk = blockIdx.x, t = threadIdx.x;
    if (blk < 512) {
        const float4* xv = (const float4*)(x + (size_t)blk * 4096);
        float s = 0.f, sq = 0.f;
#pragma unroll
        for (int i = 0; i < 4; ++i) {
            float4 v = xv[t + 256 * i];
            s  += v.x + v.y + v.z + v.w;
            sq += v.x * v.x + v.y * v.y + v.z * v.z + v.w * v.w;
        }
#pragma unroll
        for (int off = 32; off > 0; off >>= 1) {
            s  += __shfl_down(s, off, 64);
            sq += __shfl_down(sq, off, 64);
        }
        __shared__ float red[8];
        int wave = t >> 6, lane = t & 63;
        if (lane == 0) { red[wave * 2] = s; red[wave * 2 + 1] = sq; }
        __syncthreads();
        if (t == 0) {
            partials[blk * 2]     = red[0] + red[2] + red[4] + red[6];
            partials[blk * 2 + 1] = red[1] + red[3] + red[5] + red[7];
        }
    } else {
        int i = (blk - 512) * 256 + t;              // [0, 65536)
        if (i < 49152) {
            int dstBlk = i >> 9, lane = (i >> 3) & 63, j = i & 7;
            int wave = dstBlk / 24, rem = dstBlk % 24;
            int os = rem >> 2, kc = rem & 3;
            int o = wave * 96 + os * 16 + (lane & 15);
            int c = kc * 32 + (lane >> 4) * 8 + j;
            wq[i] = f2bf(qkv_w[o * 128 + c]);
        } else {
            int i2 = i - 49152;                     // [0, 16384)
            int dstBlk = i2 >> 9, lane = (i2 >> 3) & 63, j = i2 & 7;
            int wave = dstBlk >> 3, rem = dstBlk & 7;
            int os = rem >> 2, kc = rem & 3;
            int o = wave * 32 + os * 16 + (lane & 15);
            int c = kc * 32 + (lane >> 4) * 8 + j;
            wp[i2] = f2bf(proj_w[o * 128 + c]);
        }
    }
}

// ---------------- QKV projection via MFMA (inline GN finalize) ------------
// grid (128 p-tiles of 32, B) x 256. Coalesced x loads; frag-ordered weight
// loads (contiguous 1KB/wave). q,k out [b][h][n][32d] (k pre-scaled KFOLD);
// v out [b][h][32d][m] m-permuted (bits 2<->3) via LDS transpose.
__global__ __launch_bounds__(256) void qkv_mfma_kernel(
    const float* __restrict__ x, const float* __restrict__ gn_w, const float* __restrict__ gn_b,
    const u16* __restrict__ wq, const float* __restrict__ qkv_b, const float* __restrict__ partials,
    u16* __restrict__ qo, u16* __restrict__ ko, u16* __restrict__ vo) {
    __shared__ u16 xt[32 * 136];   // [p][c] pitch 136; reused as vt[128 oc][32 m] pitch 34
    __shared__ float sstats[2];
    int b = blockIdx.y, p0 = blockIdx.x * 32, t = threadIdx.x;
    const float* xb = x + (size_t)b * CH * HW;
    float4 xv[4]; int cc[4], pp[4];
#pragma unroll
    for (int i = 0; i < 4; ++i) {
        int u = t + 256 * i;
        cc[i] = u >> 3; pp[i] = (u & 7) * 4;      // coalesced: 8 lanes per c-row
        xv[i] = *(const float4*)&xb[(size_t)cc[i] * HW + p0 + pp[i]];
    }
    if (t < 64) {   // per-block redundant GN finalize (2 KB L2 read, one wave)
        float s  = partials[(b * 128 + t) * 2]     + partials[(b * 128 + 64 + t) * 2];
        float sq = partials[(b * 128 + t) * 2 + 1] + partials[(b * 128 + 64 + t) * 2 + 1];
#pragma unroll
        for (int off = 32; off > 0; off >>= 1) {
            s  += __shfl_down(s, off, 64);
            sq += __shfl_down(sq, off, 64);
        }
        if (t == 0) {
            const float invN = 1.f / (float)(CH * HW);
            float mean = s * invN;
            float var  = sq * invN - mean * mean;
            sstats[0] = mean;
            sstats[1] = rsqrtf(var + 1e-5f);
        }
    }
    __syncthreads();
    float mean = sstats[0], rstd = sstats[1];
#pragma unroll
    for (int i = 0; i < 4; ++i) {
        float sc = rstd * gn_w[cc[i]], bb = gn_b[cc[i]] - mean * sc;
        xt[(pp[i] + 0) * 136 + cc[i]] = f2bf(fmaf(xv[i].x, sc, bb));
        xt[(pp[i] + 1) * 136 + cc[i]] = f2bf(fmaf(xv[i].y, sc, bb));
        xt[(pp[i] + 2) * 136 + cc[i]] = f2bf(fmaf(xv[i].z, sc, bb));
        xt[(pp[i] + 3) * 136 + cc[i]] = f2bf(fmaf(xv[i].w, sc, bb));
    }
    __syncthreads();
    int wave = t >> 6, lane = t & 63, l16 = lane & 15, quad = lane >> 4;
    f32x4 acc[6][2];
#pragma unroll
    for (int os = 0; os < 6; ++os)
#pragma unroll
        for (int ps = 0; ps < 2; ++ps) acc[os][ps] = f32x4{0.f, 0.f, 0.f, 0.f};
#pragma unroll
    for (int kc = 0; kc < 4; ++kc) {
        bf16x8 bfr[2];
#pragma unroll
        for (int ps = 0; ps < 2; ++ps)
            bfr[ps] = *(const bf16x8*)&xt[(ps * 16 + l16) * 136 + kc * 32 + quad * 8];
#pragma unroll
        for (int os = 0; os < 6; ++os) {
            bf16x8 af = *(const bf16x8*)&wq[((wave * 6 + os) * 4 + kc) * 512 + lane * 8];
#pragma unroll
            for (int ps = 0; ps < 2; ++ps)
                acc[os][ps] = __builtin_amdgcn_mfma_f32_16x16x32_bf16(af, bfr[ps], acc[os][ps], 0, 0, 0);
        }
    }
    // ---- pass 1: q,k direct stores ----
#pragma unroll
    for (int os = 0; os < 6; ++os) {
        int obase = wave * 96 + os * 16 + quad * 4;
        int sec = obase >> 7;              // wave-uniform
        if (sec == 2) continue;
        float4 bias = *(const float4*)&qkv_b[obase];
        int oc = obase & 127, h = oc >> 5, d = oc & 31;
        float km = (sec == 1) ? KFOLD : 1.f;
#pragma unroll
        for (int ps = 0; ps < 2; ++ps) {
            int p = p0 + ps * 16 + l16;
            u16x4 pk = {f2bf((acc[os][ps][0] + bias.x) * km),
                        f2bf((acc[os][ps][1] + bias.y) * km),
                        f2bf((acc[os][ps][2] + bias.z) * km),
                        f2bf((acc[os][ps][3] + bias.w) * km)};
            *(u16x4*)((sec == 0 ? qo : ko) + ((size_t)(b * NH + h) * HW + p) * DH + d) = pk;
        }
    }
    // ---- pass 2: v through LDS transpose ----
    __syncthreads();          // xt fully consumed by all waves
    u16* vt = xt;             // [128 oc][32 m] pitch 34
    int l16p2 = (l16 & 3) | ((l16 & 4) << 1) | ((l16 & 8) >> 1);   // m-bit 2<->3 swap
#pragma unroll
    for (int os = 0; os < 6; ++os) {
        int obase = wave * 96 + os * 16 + quad * 4;
        if ((obase >> 7) != 2) continue;
        float4 bias = *(const float4*)&qkv_b[obase];
        int oc = obase & 127;
#pragma unroll
        for (int ps = 0; ps < 2; ++ps) {
            int colm = ps * 16 + l16p2;
            vt[(oc + 0) * 34 + colm] = f2bf(acc[os][ps][0] + bias.x);
            vt[(oc + 1) * 34 + colm] = f2bf(acc[os][ps][1] + bias.y);
            vt[(oc + 2) * 34 + colm] = f2bf(acc[os][ps][2] + bias.z);
            vt[(oc + 3) * 34 + colm] = f2bf(acc[os][ps][3] + bias.w);
        }
    }
    __syncthreads();
#pragma unroll
    for (int i = 0; i < 2; ++i) {
        int row = i * 64 + (t >> 2), colv = (t & 3) * 8;
        *(u16x8*)&vo[((size_t)b * CH + row) * HW + p0 + colv] = *(const u16x8*)&vt[row * 34 + colv];
    }
}

// ---------------- Flash attention, 32x32x16 MFMA, 2-way m-split, 128-m tiles
// grid (32 n-tiles of 128, 2 m-parts, 16 bh) x 256 = 1024 blocks = 4/CU.
// Conflict-free LDS pitches: K rows 36 u16 (18-bank shift), V rows 132 u16
// (2-bank shift) -- no XOR swizzle. Double-buffered, one barrier/iteration.
__global__ __launch_bounds__(256, 4) void attn_mfma_kernel(
    const u16* __restrict__ q, const u16* __restrict__ k, const u16* __restrict__ v,
    u16* __restrict__ Op, float* __restrict__ lp) {
    __shared__ u16 smem[17664];  // K: 2 x 128*36 @0; V: 2 x 32*132 @9216; epi tb @0
    int bh = blockIdx.z, mpart = blockIdx.y, t = threadIdx.x;
    int wave = t >> 6, lane = t & 63, l31 = lane & 31, hf = lane >> 5;
    const u16* qb = q + (size_t)bh * HW * DH;
    const u16* kb = k + (size_t)bh * HW * DH;   // pre-scaled by KFOLD
    const u16* vb = v + (size_t)bh * DH * HW;
    int n_g = blockIdx.x * 128 + wave * 32 + l31;
    int m_base = mpart * 2048;

    bf16x8 bq0 = *(const bf16x8*)&qb[(size_t)n_g * DH + hf * 8];
    bf16x8 bq1 = *(const bf16x8*)&qb[(size_t)n_g * DH + 16 + hf * 8];

    // staging coords: K[128 m][32 d] pitch 36; V[32 d][128 m] pitch 132
    int km_ = t >> 2, kg_ = t & 3;
    int kw0 = km_ * 36 + kg_ * 8, kw1 = kw0 + 64 * 36;
    const u16* kgp = kb + (size_t)(m_base + km_) * DH + kg_ * 8;
    int vd_ = t >> 3, vg_ = t & 7;
    int vw0 = vd_ * 132 + vg_ * 8, vw1 = vw0 + 64;
    const u16* vgp = vb + (size_t)vd_ * HW + m_base + vg_ * 8;

    // frag-read offsets (no swizzle)
    int kro[2][2], vro[4];
#pragma unroll
    for (int ms = 0; ms < 2; ++ms)
#pragma unroll
        for (int kc = 0; kc < 2; ++kc)
            kro[ms][kc] = (ms * 32 + l31) * 36 + (2 * kc + hf) * 8;
#pragma unroll
    for (int kc = 0; kc < 4; ++kc)
        vro[kc] = l31 * 132 + (2 * kc + hf) * 8;

    const f32x16 zero16 = {0.f,0.f,0.f,0.f,0.f,0.f,0.f,0.f,0.f,0.f,0.f,0.f,0.f,0.f,0.f,0.f};
    f32x16 accO = zero16;
    float l_part = 0.f;

    bf16x8 kregA = *(const bf16x8*)kgp;
    bf16x8 kregB = *(const bf16x8*)(kgp + 64 * DH);
    bf16x8 vregA = *(const bf16x8*)vgp;
    bf16x8 vregB = *(const bf16x8*)(vgp + 64);

    for (int it = 0; it < 16; ++it) {
        u16* Ksb = smem + (it & 1) * 4608;
        u16* Vsb = smem + 9216 + (it & 1) * 4224;
        *(bf16x8*)&Ksb[kw0] = kregA;
        *(bf16x8*)&Ksb[kw1] = kregB;
        *(bf16x8*)&Vsb[vw0] = vregA;
        *(bf16x8*)&Vsb[vw1] = vregB;
        __syncthreads();
        if (it < 15) {   // issue next-tile loads AFTER barrier
            const u16* kp = kgp + (size_t)(it + 1) * 128 * DH;
            kregA = *(const bf16x8*)kp;
            kregB = *(const bf16x8*)(kp + 64 * DH);
            const u16* vp = vgp + (it + 1) * 128;
            vregA = *(const bf16x8*)vp;
            vregB = *(const bf16x8*)(vp + 64);
        }
#pragma unroll
        for (int h = 0; h < 2; ++h) {       // two 64-m subtiles
            const u16* Kh = Ksb + h * 2304;
            f32x16 s0, s1;
            {
                bf16x8 a00 = *(const bf16x8*)&Kh[kro[0][0]];
                bf16x8 a01 = *(const bf16x8*)&Kh[kro[0][1]];
                s0 = __builtin_amdgcn_mfma_f32_32x32x16_bf16(a00, bq0, zero16, 0, 0, 0);
                s0 = __builtin_amdgcn_mfma_f32_32x32x16_bf16(a01, bq1, s0, 0, 0, 0);
                bf16x8 a10 = *(const bf16x8*)&Kh[kro[1][0]];
                bf16x8 a11 = *(const bf16x8*)&Kh[kro[1][1]];
                s1 = __builtin_amdgcn_mfma_f32_32x32x16_bf16(a10, bq0, zero16, 0, 0, 0);
                s1 = __builtin_amdgcn_mfma_f32_32x32x16_bf16(a11, bq1, s1, 0, 0, 0);
            }
            unsigned pk[2][8];
#pragma unroll
            for (int qq = 0; qq < 8; ++qq) {
                float e0 = FASTEXP(s0[2 * qq]), e1 = FASTEXP(s0[2 * qq + 1]);
                l_part += e0 + e1;
                pk[0][qq] = pack2bf_t(e0, e1);
                float f0 = FASTEXP(s1[2 * qq]), f1 = FASTEXP(s1[2 * qq + 1]);
                l_part += f0 + f1;
                pk[1][qq] = pack2bf_t(f0, f1);
            }
#pragma unroll
            for (int kc = 0; kc < 4; ++kc) {
                int ms = kc >> 1, Qb = 4 * (kc & 1);
                union { unsigned u[4]; bf16x8 v; } bu;
                bu.u[0] = pk[ms][Qb + 0];
                bu.u[1] = pk[ms][Qb + 1];
                bu.u[2] = pk[ms][Qb + 2];
                bu.u[3] = pk[ms][Qb + 3];
                bf16x8 av = *(const bf16x8*)&Vsb[vro[kc] + h * 64];
                accO = __builtin_amdgcn_mfma_f32_32x32x16_bf16(av, bu.v, accO, 0, 0, 0);
            }
        }
    }
    l_part += __shfl_xor(l_part, 32, 64);
    if (hf == 0) lp[((size_t)bh * HW + n_g) * 2 + mpart] = l_part;
    // epilogue: transpose O^T (C-layout) -> [n][d] in LDS, coalesced store
    __syncthreads();
    u16* tb = smem;                      // [128 n][32 d] pitch 36
    int nloc = wave * 32 + l31;
#pragma unroll
    for (int r = 0; r < 16; ++r) {
        int d = (r & 3) + 8 * (r >> 2) + 4 * hf;
        tb[nloc * 36 + d] = f2bf(accO[r]);
    }
    __syncthreads();
    size_t obase = ((size_t)(mpart * 16 + bh) * HW + blockIdx.x * 128) * 32;
#pragma unroll
    for (int i = 0; i < 2; ++i) {
        int row = i * 64 + (t >> 2), col = (t & 3) * 8;
        *(u16x8*)&Op[obase + (size_t)row * 32 + col] = *(const u16x8*)&tb[row * 36 + col];
    }
}

// ---------------- Output projection (fused combine) + bias + residual ----
// grid (128 p-tiles of 32, B) x 256. Coalesced Op[part][bh][n][32d] reads,
// 2-part fp32 sum, divide by summed l, LDS tile [p][c], MFMA GEMM.
__global__ __launch_bounds__(256) void proj_mfma_kernel(
    const u16* __restrict__ Op, const float* __restrict__ lp,
    const u16* __restrict__ wp, const float* __restrict__ proj_b,
    const float* __restrict__ x, float* __restrict__ out) {
    __shared__ u16 at_t[32 * 136];   // [p][c] pitch 136
    int b = blockIdx.y, p0 = blockIdx.x * 32, t = threadIdx.x;
#pragma unroll
    for (int i = 0; i < 2; ++i) {
        int u = t + 256 * i;                 // 512 units: p(32) x hh(4) x chunk(4)
        int p = u >> 4, hh = (u >> 2) & 3, ch = u & 3;
        int bh = b * NH + hh;
        size_t nidx = (size_t)bh * HW + p0 + p;
        float2 l2 = *(const float2*)&lp[nidx * 2];
        float lsum = l2.x + l2.y;
        float sum8[8] = {0.f,0.f,0.f,0.f,0.f,0.f,0.f,0.f};
#pragma unroll
        for (int part = 0; part < 2; ++part) {
            u16x8 ov = *(const u16x8*)&Op[((size_t)(part * 16 + bh) * HW + p0 + p) * 32 + ch * 8];
#pragma unroll
            for (int j = 0; j < 8; ++j) sum8[j] += bf2f(ov[j]);
        }
        float rin = RCPF(lsum);
#pragma unroll
        for (int j = 0; j < 8; ++j)
            at_t[p * 136 + (ch * 8 + j) * 4 + hh] = f2bf(sum8[j] * rin);
    }
    __syncthreads();
    int wave = t >> 6, lane = t & 63, l16 = lane & 15, quad = lane >> 4;
    f32x4 acc[2][2];
#pragma unroll
    for (int os = 0; os < 2; ++os)
#pragma unroll
        for (int ps = 0; ps < 2; ++ps) acc[os][ps] = f32x4{0.f, 0.f, 0.f, 0.f};
#pragma unroll
    for (int kc = 0; kc < 4; ++kc) {
        bf16x8 bfr[2];
#pragma unroll
        for (int ps = 0; ps < 2; ++ps)
            bfr[ps] = *(const bf16x8*)&at_t[(ps * 16 + l16) * 136 + kc * 32 + quad * 8];
#pragma unroll
        for (int os = 0; os < 2; ++os) {
            bf16x8 af = *(const bf16x8*)&wp[((wave * 2 + os) * 4 + kc) * 512 + lane * 8];
#pragma unroll
            for (int ps = 0; ps < 2; ++ps)
                acc[os][ps] = __builtin_amdgcn_mfma_f32_16x16x32_bf16(af, bfr[ps], acc[os][ps], 0, 0, 0);
        }
    }
#pragma unroll
    for (int os = 0; os < 2; ++os) {
        int obase = wave * 32 + os * 16 + quad * 4;
#pragma unroll
        for (int ps = 0; ps < 2; ++ps) {
            int p = p0 + ps * 16 + l16;
#pragma unroll
            for (int r = 0; r < 4; ++r) {
                size_t idx = ((size_t)b * CH + obase + r) * HW + p;
                out[idx] = acc[os][ps][r] + proj_b[obase + r] + x[idx];
            }
        }
    }
}

extern "C" void kernel_launch(void* const* d_in, const int* in_sizes, int n_in,
                              void* d_out, int out_size, void* d_ws, size_t ws_size,
                              hipStream_t stream) {
    const float* x      = (const float*)d_in[0];
    const float* gn_w   = (const float*)d_in[1];
    const float* gn_b   = (const float*)d_in[2];
    const float* qkv_w  = (const float*)d_in[3];
    const float* qkv_b  = (const float*)d_in[4];
    const float* proj_w = (const float*)d_in[5];
    const float* proj_b = (const float*)d_in[6];
    float* out = (float*)d_out;

    char* W = (char*)d_ws;
    float* partials = (float*)(W + 0);                 // 4 KB
    u16*   wq       = (u16*)(W + 8192);                // 96 KB (frag-swizzled)
    u16*   wp       = (u16*)(W + 8192 + 98304);        // 32 KB (frag-swizzled)
    u16*   qo       = (u16*)(W + 139264);              // 4 MB each
    u16*   ko       = qo + (size_t)2097152;
    u16*   vo       = ko + (size_t)2097152;
    u16*   Op       = vo + (size_t)2097152;            // 2 parts x 4 MB = 8 MB
    float* lp       = (float*)(Op + (size_t)2 * 2097152);  // 512 KB -> total ~25 MB

    hipLaunchKernelGGL(prep_kernel,      dim3(768),       dim3(256), 0, stream,
                       x, partials, qkv_w, proj_w, wq, wp);
    hipLaunchKernelGGL(qkv_mfma_kernel,  dim3(128, 4),    dim3(256), 0, stream,
                       x, gn_w, gn_b, wq, qkv_b, partials, qo, ko, vo);
    hipLaunchKernelGGL(attn_mfma_kernel, dim3(32, 2, 16), dim3(256), 0, stream,
                       qo, ko, vo, Op, lp);
    hipLaunchKernelGGL(proj_mfma_kernel, dim3(128, 4),    dim3(256), 0, stream,
                       Op, lp, wp, proj_b, x, out);
}

// Round 10
// 137.406 us; speedup vs baseline: 1.6647x; 1.6647x over previous
//
#include <hip/hip_runtime.h>
#include <math.h>

#define HW 4096
#define CH 128
#define NH 4
#define DH 32

typedef unsigned short u16;
typedef __attribute__((ext_vector_type(8))) short bf16x8;   // 8 bf16 in 4 VGPRs
typedef __attribute__((ext_vector_type(4))) float f32x4;
typedef __attribute__((ext_vector_type(16))) float f32x16;
typedef __attribute__((ext_vector_type(4))) unsigned short u16x4;
typedef __attribute__((ext_vector_type(8))) unsigned short u16x8;

// raw v_exp_f32 (args are in [-1,1]; no range fixups needed)
#if __has_builtin(__builtin_amdgcn_exp2f)
#define KFOLD (0.17677669529663687f * 1.4426950408889634f)   // scale * log2(e)
#define FASTEXP(x) __builtin_amdgcn_exp2f(x)
#else
#define KFOLD 0.17677669529663687f                            // scale only
#define FASTEXP(x) __expf(x)
#endif

#if __has_builtin(__builtin_amdgcn_rcpf)
#define RCPF(x) __builtin_amdgcn_rcpf(x)
#else
#define RCPF(x) (1.f / (x))
#endif

__device__ __forceinline__ u16 f2bf(float f) {
    union { float f; unsigned u; } a; a.f = f;
    unsigned u = a.u;
    unsigned r = u + 0x7FFFu + ((u >> 16) & 1u);   // RNE
    return (u16)(r >> 16);
}
__device__ __forceinline__ float bf2f(u16 u) {
    union { unsigned u; float f; } a; a.u = ((unsigned)u) << 16;
    return a.f;
}
// pack two positive floats to bf16 pair by TRUNCATION (1 v_perm): low=a, high=b
__device__ __forceinline__ unsigned pack2bf_t(float a, float b) {
    union { float f; unsigned u; } ua, ub; ua.f = a; ub.f = b;
    return __builtin_amdgcn_perm(ub.u, ua.u, 0x07060302u);
}

// ---------------- Fused: weight frag-swizzle conversion + GN partials -----
// Weights are stored in MFMA A-fragment order: [(wave*NOS+os)*4+kc][lane][8]
// so consumer waves load one contiguous 1KB stream per fragment.
__global__ __launch_bounds__(256) void prep_kernel(
    const float* __restrict__ x, float* __restrict__ partials,
    const float* __restrict__ qkv_w, const float* __restrict__ proj_w,
    u16* __restrict__ wq, u16* __restrict__ wp) {
    int blk = blockIdx.x, t = threadIdx.x;
    if (blk < 512) {
        const float4* xv = (const float4*)(x + (size_t)blk * 4096);
        float s = 0.f, sq = 0.f;
#pragma unroll
        for (int i = 0; i < 4; ++i) {
            float4 v = xv[t + 256 * i];
            s  += v.x + v.y + v.z + v.w;
            sq += v.x * v.x + v.y * v.y + v.z * v.z + v.w * v.w;
        }
#pragma unroll
        for (int off = 32; off > 0; off >>= 1) {
            s  += __shfl_down(s, off, 64);
            sq += __shfl_down(sq, off, 64);
        }
        __shared__ float red[8];
        int wave = t >> 6, lane = t & 63;
        if (lane == 0) { red[wave * 2] = s; red[wave * 2 + 1] = sq; }
        __syncthreads();
        if (t == 0) {
            partials[blk * 2]     = red[0] + red[2] + red[4] + red[6];
            partials[blk * 2 + 1] = red[1] + red[3] + red[5] + red[7];
        }
    } else {
        int i = (blk - 512) * 256 + t;              // [0, 65536)
        if (i < 49152) {
            int dstBlk = i >> 9, lane = (i >> 3) & 63, j = i & 7;
            int wave = dstBlk / 24, rem = dstBlk % 24;
            int os = rem >> 2, kc = rem & 3;
            int o = wave * 96 + os * 16 + (lane & 15);
            int c = kc * 32 + (lane >> 4) * 8 + j;
            wq[i] = f2bf(qkv_w[o * 128 + c]);
        } else {
            int i2 = i - 49152;                     // [0, 16384)
            int dstBlk = i2 >> 9, lane = (i2 >> 3) & 63, j = i2 & 7;
            int wave = dstBlk >> 3, rem = dstBlk & 7;
            int os = rem >> 2, kc = rem & 3;
            int o = wave * 32 + os * 16 + (lane & 15);
            int c = kc * 32 + (lane >> 4) * 8 + j;
            wp[i2] = f2bf(proj_w[o * 128 + c]);
        }
    }
}

// ---------------- QKV projection via MFMA (inline GN finalize) ------------
// grid (128 p-tiles of 32, B) x 256. Coalesced x loads; frag-ordered weight
// loads (contiguous 1KB/wave). q,k out [b][h][n][32d] (k pre-scaled KFOLD);
// v out [b][h][32d][m] m-permuted (bits 2<->3) via LDS transpose.
__global__ __launch_bounds__(256) void qkv_mfma_kernel(
    const float* __restrict__ x, const float* __restrict__ gn_w, const float* __restrict__ gn_b,
    const u16* __restrict__ wq, const float* __restrict__ qkv_b, const float* __restrict__ partials,
    u16* __restrict__ qo, u16* __restrict__ ko, u16* __restrict__ vo) {
    __shared__ u16 xt[32 * 136];   // [p][c] pitch 136; reused as vt[128 oc][32 m] pitch 34
    __shared__ float sstats[2];
    int b = blockIdx.y, p0 = blockIdx.x * 32, t = threadIdx.x;
    const float* xb = x + (size_t)b * CH * HW;
    float4 xv[4]; int cc[4], pp[4];
#pragma unroll
    for (int i = 0; i < 4; ++i) {
        int u = t + 256 * i;
        cc[i] = u >> 3; pp[i] = (u & 7) * 4;      // coalesced: 8 lanes per c-row
        xv[i] = *(const float4*)&xb[(size_t)cc[i] * HW + p0 + pp[i]];
    }
    if (t < 64) {   // per-block redundant GN finalize (2 KB L2 read, one wave)
        float s  = partials[(b * 128 + t) * 2]     + partials[(b * 128 + 64 + t) * 2];
        float sq = partials[(b * 128 + t) * 2 + 1] + partials[(b * 128 + 64 + t) * 2 + 1];
#pragma unroll
        for (int off = 32; off > 0; off >>= 1) {
            s  += __shfl_down(s, off, 64);
            sq += __shfl_down(sq, off, 64);
        }
        if (t == 0) {
            const float invN = 1.f / (float)(CH * HW);
            float mean = s * invN;
            float var  = sq * invN - mean * mean;
            sstats[0] = mean;
            sstats[1] = rsqrtf(var + 1e-5f);
        }
    }
    __syncthreads();
    float mean = sstats[0], rstd = sstats[1];
#pragma unroll
    for (int i = 0; i < 4; ++i) {
        float sc = rstd * gn_w[cc[i]], bb = gn_b[cc[i]] - mean * sc;
        xt[(pp[i] + 0) * 136 + cc[i]] = f2bf(fmaf(xv[i].x, sc, bb));
        xt[(pp[i] + 1) * 136 + cc[i]] = f2bf(fmaf(xv[i].y, sc, bb));
        xt[(pp[i] + 2) * 136 + cc[i]] = f2bf(fmaf(xv[i].z, sc, bb));
        xt[(pp[i] + 3) * 136 + cc[i]] = f2bf(fmaf(xv[i].w, sc, bb));
    }
    __syncthreads();
    int wave = t >> 6, lane = t & 63, l16 = lane & 15, quad = lane >> 4;
    f32x4 acc[6][2];
#pragma unroll
    for (int os = 0; os < 6; ++os)
#pragma unroll
        for (int ps = 0; ps < 2; ++ps) acc[os][ps] = f32x4{0.f, 0.f, 0.f, 0.f};
#pragma unroll
    for (int kc = 0; kc < 4; ++kc) {
        bf16x8 bfr[2];
#pragma unroll
        for (int ps = 0; ps < 2; ++ps)
            bfr[ps] = *(const bf16x8*)&xt[(ps * 16 + l16) * 136 + kc * 32 + quad * 8];
#pragma unroll
        for (int os = 0; os < 6; ++os) {
            bf16x8 af = *(const bf16x8*)&wq[((wave * 6 + os) * 4 + kc) * 512 + lane * 8];
#pragma unroll
            for (int ps = 0; ps < 2; ++ps)
                acc[os][ps] = __builtin_amdgcn_mfma_f32_16x16x32_bf16(af, bfr[ps], acc[os][ps], 0, 0, 0);
        }
    }
    // ---- pass 1: q,k direct stores ----
#pragma unroll
    for (int os = 0; os < 6; ++os) {
        int obase = wave * 96 + os * 16 + quad * 4;
        int sec = obase >> 7;              // wave-uniform
        if (sec == 2) continue;
        float4 bias = *(const float4*)&qkv_b[obase];
        int oc = obase & 127, h = oc >> 5, d = oc & 31;
        float km = (sec == 1) ? KFOLD : 1.f;
#pragma unroll
        for (int ps = 0; ps < 2; ++ps) {
            int p = p0 + ps * 16 + l16;
            u16x4 pk = {f2bf((acc[os][ps][0] + bias.x) * km),
                        f2bf((acc[os][ps][1] + bias.y) * km),
                        f2bf((acc[os][ps][2] + bias.z) * km),
                        f2bf((acc[os][ps][3] + bias.w) * km)};
            *(u16x4*)((sec == 0 ? qo : ko) + ((size_t)(b * NH + h) * HW + p) * DH + d) = pk;
        }
    }
    // ---- pass 2: v through LDS transpose ----
    __syncthreads();          // xt fully consumed by all waves
    u16* vt = xt;             // [128 oc][32 m] pitch 34
    int l16p2 = (l16 & 3) | ((l16 & 4) << 1) | ((l16 & 8) >> 1);   // m-bit 2<->3 swap
#pragma unroll
    for (int os = 0; os < 6; ++os) {
        int obase = wave * 96 + os * 16 + quad * 4;
        if ((obase >> 7) != 2) continue;
        float4 bias = *(const float4*)&qkv_b[obase];
        int oc = obase & 127;
#pragma unroll
        for (int ps = 0; ps < 2; ++ps) {
            int colm = ps * 16 + l16p2;
            vt[(oc + 0) * 34 + colm] = f2bf(acc[os][ps][0] + bias.x);
            vt[(oc + 1) * 34 + colm] = f2bf(acc[os][ps][1] + bias.y);
            vt[(oc + 2) * 34 + colm] = f2bf(acc[os][ps][2] + bias.z);
            vt[(oc + 3) * 34 + colm] = f2bf(acc[os][ps][3] + bias.w);
        }
    }
    __syncthreads();
#pragma unroll
    for (int i = 0; i < 2; ++i) {
        int row = i * 64 + (t >> 2), colv = (t & 3) * 8;
        *(u16x8*)&vo[((size_t)b * CH + row) * HW + p0 + colv] = *(const u16x8*)&vt[row * 34 + colv];
    }
}

// ---------------- Flash attention, 32x32x16 MFMA, 2-way m-split, 128-m tiles
// grid (32 n-tiles of 128, 2 m-parts, 16 bh) x 256 = 1024 blocks = 4/CU.
// LDS pitches are BOTH conflict-aware AND 16B-multiples (R9 lesson: pitch 36/132
// broke b128 alignment -> 3x slowdown). K pitch 40 u16 (80 B = 20-bank shift:
// 8-lane phase hits all 32 banks), V pitch 136 u16 (272 B = 4-bank shift).
__global__ __launch_bounds__(256, 4) void attn_mfma_kernel(
    const u16* __restrict__ q, const u16* __restrict__ k, const u16* __restrict__ v,
    u16* __restrict__ Op, float* __restrict__ lp) {
    __shared__ u16 smem[18944];  // K: 2 x 128*40 @0; V: 2 x 32*136 @10240; epi tb @0
    int bh = blockIdx.z, mpart = blockIdx.y, t = threadIdx.x;
    int wave = t >> 6, lane = t & 63, l31 = lane & 31, hf = lane >> 5;
    const u16* qb = q + (size_t)bh * HW * DH;
    const u16* kb = k + (size_t)bh * HW * DH;   // pre-scaled by KFOLD
    const u16* vb = v + (size_t)bh * DH * HW;
    int n_g = blockIdx.x * 128 + wave * 32 + l31;
    int m_base = mpart * 2048;

    bf16x8 bq0 = *(const bf16x8*)&qb[(size_t)n_g * DH + hf * 8];
    bf16x8 bq1 = *(const bf16x8*)&qb[(size_t)n_g * DH + 16 + hf * 8];

    // staging coords: K[128 m][32 d] pitch 40; V[32 d][128 m] pitch 136
    int km_ = t >> 2, kg_ = t & 3;
    int kw0 = km_ * 40 + kg_ * 8, kw1 = kw0 + 64 * 40;
    const u16* kgp = kb + (size_t)(m_base + km_) * DH + kg_ * 8;
    int vd_ = t >> 3, vg_ = t & 7;
    int vw0 = vd_ * 136 + vg_ * 8, vw1 = vw0 + 64;
    const u16* vgp = vb + (size_t)vd_ * HW + m_base + vg_ * 8;

    // frag-read offsets (no swizzle; pitches carry the bank rotation)
    int kro[2][2], vro[4];
#pragma unroll
    for (int ms = 0; ms < 2; ++ms)
#pragma unroll
        for (int kc = 0; kc < 2; ++kc)
            kro[ms][kc] = (ms * 32 + l31) * 40 + (2 * kc + hf) * 8;
#pragma unroll
    for (int kc = 0; kc < 4; ++kc)
        vro[kc] = l31 * 136 + (2 * kc + hf) * 8;

    const f32x16 zero16 = {0.f,0.f,0.f,0.f,0.f,0.f,0.f,0.f,0.f,0.f,0.f,0.f,0.f,0.f,0.f,0.f};
    f32x16 accO = zero16;
    float l_part = 0.f;

    bf16x8 kregA = *(const bf16x8*)kgp;
    bf16x8 kregB = *(const bf16x8*)(kgp + 64 * DH);
    bf16x8 vregA = *(const bf16x8*)vgp;
    bf16x8 vregB = *(const bf16x8*)(vgp + 64);

    for (int it = 0; it < 16; ++it) {
        u16* Ksb = smem + (it & 1) * 5120;
        u16* Vsb = smem + 10240 + (it & 1) * 4352;
        *(bf16x8*)&Ksb[kw0] = kregA;
        *(bf16x8*)&Ksb[kw1] = kregB;
        *(bf16x8*)&Vsb[vw0] = vregA;
        *(bf16x8*)&Vsb[vw1] = vregB;
        __syncthreads();
        if (it < 15) {   // issue next-tile loads AFTER barrier
            const u16* kp = kgp + (size_t)(it + 1) * 128 * DH;
            kregA = *(const bf16x8*)kp;
            kregB = *(const bf16x8*)(kp + 64 * DH);
            const u16* vp = vgp + (it + 1) * 128;
            vregA = *(const bf16x8*)vp;
            vregB = *(const bf16x8*)(vp + 64);
        }
#pragma unroll
        for (int h = 0; h < 2; ++h) {       // two 64-m subtiles
            const u16* Kh = Ksb + h * 2560;
            f32x16 s0, s1;
            {
                bf16x8 a00 = *(const bf16x8*)&Kh[kro[0][0]];
                bf16x8 a01 = *(const bf16x8*)&Kh[kro[0][1]];
                s0 = __builtin_amdgcn_mfma_f32_32x32x16_bf16(a00, bq0, zero16, 0, 0, 0);
                s0 = __builtin_amdgcn_mfma_f32_32x32x16_bf16(a01, bq1, s0, 0, 0, 0);
                bf16x8 a10 = *(const bf16x8*)&Kh[kro[1][0]];
                bf16x8 a11 = *(const bf16x8*)&Kh[kro[1][1]];
                s1 = __builtin_amdgcn_mfma_f32_32x32x16_bf16(a10, bq0, zero16, 0, 0, 0);
                s1 = __builtin_amdgcn_mfma_f32_32x32x16_bf16(a11, bq1, s1, 0, 0, 0);
            }
            unsigned pk[2][8];
#pragma unroll
            for (int qq = 0; qq < 8; ++qq) {
                float e0 = FASTEXP(s0[2 * qq]), e1 = FASTEXP(s0[2 * qq + 1]);
                l_part += e0 + e1;
                pk[0][qq] = pack2bf_t(e0, e1);
                float f0 = FASTEXP(s1[2 * qq]), f1 = FASTEXP(s1[2 * qq + 1]);
                l_part += f0 + f1;
                pk[1][qq] = pack2bf_t(f0, f1);
            }
#pragma unroll
            for (int kc = 0; kc < 4; ++kc) {
                int ms = kc >> 1, Qb = 4 * (kc & 1);
                union { unsigned u[4]; bf16x8 v; } bu;
                bu.u[0] = pk[ms][Qb + 0];
                bu.u[1] = pk[ms][Qb + 1];
                bu.u[2] = pk[ms][Qb + 2];
                bu.u[3] = pk[ms][Qb + 3];
                bf16x8 av = *(const bf16x8*)&Vsb[vro[kc] + h * 64];
                accO = __builtin_amdgcn_mfma_f32_32x32x16_bf16(av, bu.v, accO, 0, 0, 0);
            }
        }
    }
    l_part += __shfl_xor(l_part, 32, 64);
    if (hf == 0) lp[((size_t)bh * HW + n_g) * 2 + mpart] = l_part;
    // epilogue: transpose O^T (C-layout) -> [n][d] in LDS, coalesced store
    __syncthreads();
    u16* tb = smem;                      // [128 n][32 d] pitch 40
    int nloc = wave * 32 + l31;
#pragma unroll
    for (int r = 0; r < 16; ++r) {
        int d = (r & 3) + 8 * (r >> 2) + 4 * hf;
        tb[nloc * 40 + d] = f2bf(accO[r]);
    }
    __syncthreads();
    size_t obase = ((size_t)(mpart * 16 + bh) * HW + blockIdx.x * 128) * 32;
#pragma unroll
    for (int i = 0; i < 2; ++i) {
        int row = i * 64 + (t >> 2), col = (t & 3) * 8;
        *(u16x8*)&Op[obase + (size_t)row * 32 + col] = *(const u16x8*)&tb[row * 40 + col];
    }
}

// ---------------- Output projection (fused combine) + bias + residual ----
// grid (128 p-tiles of 32, B) x 256. Coalesced Op[part][bh][n][32d] reads,
// 2-part fp32 sum, divide by summed l, LDS tile [p][c], MFMA GEMM.
__global__ __launch_bounds__(256) void proj_mfma_kernel(
    const u16* __restrict__ Op, const float* __restrict__ lp,
    const u16* __restrict__ wp, const float* __restrict__ proj_b,
    const float* __restrict__ x, float* __restrict__ out) {
    __shared__ u16 at_t[32 * 136];   // [p][c] pitch 136
    int b = blockIdx.y, p0 = blockIdx.x * 32, t = threadIdx.x;
#pragma unroll
    for (int i = 0; i < 2; ++i) {
        int u = t + 256 * i;                 // 512 units: p(32) x hh(4) x chunk(4)
        int p = u >> 4, hh = (u >> 2) & 3, ch = u & 3;
        int bh = b * NH + hh;
        size_t nidx = (size_t)bh * HW + p0 + p;
        float2 l2 = *(const float2*)&lp[nidx * 2];
        float lsum = l2.x + l2.y;
        float sum8[8] = {0.f,0.f,0.f,0.f,0.f,0.f,0.f,0.f};
#pragma unroll
        for (int part = 0; part < 2; ++part) {
            u16x8 ov = *(const u16x8*)&Op[((size_t)(part * 16 + bh) * HW + p0 + p) * 32 + ch * 8];
#pragma unroll
            for (int j = 0; j < 8; ++j) sum8[j] += bf2f(ov[j]);
        }
        float rin = RCPF(lsum);
#pragma unroll
        for (int j = 0; j < 8; ++j)
            at_t[p * 136 + (ch * 8 + j) * 4 + hh] = f2bf(sum8[j] * rin);
    }
    __syncthreads();
    int wave = t >> 6, lane = t & 63, l16 = lane & 15, quad = lane >> 4;
    f32x4 acc[2][2];
#pragma unroll
    for (int os = 0; os < 2; ++os)
#pragma unroll
        for (int ps = 0; ps < 2; ++ps) acc[os][ps] = f32x4{0.f, 0.f, 0.f, 0.f};
#pragma unroll
    for (int kc = 0; kc < 4; ++kc) {
        bf16x8 bfr[2];
#pragma unroll
        for (int ps = 0; ps < 2; ++ps)
            bfr[ps] = *(const bf16x8*)&at_t[(ps * 16 + l16) * 136 + kc * 32 + quad * 8];
#pragma unroll
        for (int os = 0; os < 2; ++os) {
            bf16x8 af = *(const bf16x8*)&wp[((wave * 2 + os) * 4 + kc) * 512 + lane * 8];
#pragma unroll
            for (int ps = 0; ps < 2; ++ps)
                acc[os][ps] = __builtin_amdgcn_mfma_f32_16x16x32_bf16(af, bfr[ps], acc[os][ps], 0, 0, 0);
        }
    }
#pragma unroll
    for (int os = 0; os < 2; ++os) {
        int obase = wave * 32 + os * 16 + quad * 4;
#pragma unroll
        for (int ps = 0; ps < 2; ++ps) {
            int p = p0 + ps * 16 + l16;
#pragma unroll
            for (int r = 0; r < 4; ++r) {
                size_t idx = ((size_t)b * CH + obase + r) * HW + p;
                out[idx] = acc[os][ps][r] + proj_b[obase + r] + x[idx];
            }
        }
    }
}

extern "C" void kernel_launch(void* const* d_in, const int* in_sizes, int n_in,
                              void* d_out, int out_size, void* d_ws, size_t ws_size,
                              hipStream_t stream) {
    const float* x      = (const float*)d_in[0];
    const float* gn_w   = (const float*)d_in[1];
    const float* gn_b   = (const float*)d_in[2];
    const float* qkv_w  = (const float*)d_in[3];
    const float* qkv_b  = (const float*)d_in[4];
    const float* proj_w = (const float*)d_in[5];
    const float* proj_b = (const float*)d_in[6];
    float* out = (float*)d_out;

    char* W = (char*)d_ws;
    float* partials = (float*)(W + 0);                 // 4 KB
    u16*   wq       = (u16*)(W + 8192);                // 96 KB (frag-swizzled)
    u16*   wp       = (u16*)(W + 8192 + 98304);        // 32 KB (frag-swizzled)
    u16*   qo       = (u16*)(W + 139264);              // 4 MB each
    u16*   ko       = qo + (size_t)2097152;
    u16*   vo       = ko + (size_t)2097152;
    u16*   Op       = vo + (size_t)2097152;            // 2 parts x 4 MB = 8 MB
    float* lp       = (float*)(Op + (size_t)2 * 2097152);  // 512 KB -> total ~25 MB

    hipLaunchKernelGGL(prep_kernel,      dim3(768),       dim3(256), 0, stream,
                       x, partials, qkv_w, proj_w, wq, wp);
    hipLaunchKernelGGL(qkv_mfma_kernel,  dim3(128, 4),    dim3(256), 0, stream,
                       x, gn_w, gn_b, wq, qkv_b, partials, qo, ko, vo);
    hipLaunchKernelGGL(attn_mfma_kernel, dim3(32, 2, 16), dim3(256), 0, stream,
                       qo, ko, vo, Op, lp);
    hipLaunchKernelGGL(proj_mfma_kernel, dim3(128, 4),    dim3(256), 0, stream,
                       Op, lp, wp, proj_b, x, out);
}